// Round 11
// baseline (292.631 us; speedup 1.0000x reference)
//
#include <hip/hip_runtime.h>
#include <math.h>

#define MAX_ITER 20
#define EPS_W 1e-3f
#define CLAMP_MIN 1e-4f
#define CLAMP_MAX 1e4f

#define E 16
#define CGBLK 256
#define CHUNK (E * CGBLK)  // 4096 elems/block; bpb = K/CHUNK = 32

__device__ __forceinline__ float sp_w(float u) {
    float sp = fmaxf(u, 0.f) + log1pf(expf(-fabsf(u)));
    float w = sp + EPS_W;
    return fminf(fmaxf(w, CLAMP_MIN), CLAMP_MAX);
}
__device__ __forceinline__ float nn(float x) { return (x == x) ? x : 0.f; }

// SYSTEM-scope relaxed atomics: cache-bypassing, coherence-point direct.
// (Measured r6->r7: poll rounds 21us -> 3.4us.)
__device__ __forceinline__ unsigned long long sys_ld64(const unsigned long long* p) {
    return __hip_atomic_load(p, __ATOMIC_RELAXED, __HIP_MEMORY_SCOPE_SYSTEM);
}
__device__ __forceinline__ unsigned long long sys_ld64_acq(const unsigned long long* p) {
    return __hip_atomic_load(p, __ATOMIC_ACQUIRE, __HIP_MEMORY_SCOPE_SYSTEM);
}
__device__ __forceinline__ void sys_st64(unsigned long long* p, unsigned long long v) {
    __hip_atomic_store(p, v, __ATOMIC_RELAXED, __HIP_MEMORY_SCOPE_SYSTEM);
}
__device__ __forceinline__ unsigned long long poll_tag(const unsigned long long* p, unsigned gen) {
    unsigned long long v; int s = 0;
    for (;;) {
        v = sys_ld64(p);
        if ((unsigned)(v >> 32) >= gen) return v;
        if ((++s & 63) == 0) {               // livelock insurance only
            v = sys_ld64_acq(p);
            if ((unsigned)(v >> 32) >= gen) return v;
        }
        __builtin_amdgcn_s_sleep(1);
    }
}
__device__ __forceinline__ unsigned long long mkword(unsigned gen, float f) {
    return ((unsigned long long)gen << 32) | (unsigned long long)__float_as_uint(f);
}
__device__ __forceinline__ float payload(unsigned long long v) {
    return __uint_as_float((unsigned)v);
}

// valid on tid 0 only; block = 256 threads (4 waves)
__device__ __forceinline__ float blockReduceSum(float v) {
    #pragma unroll
    for (int off = 32; off > 0; off >>= 1) v += __shfl_down(v, off, 64);
    __shared__ float smem[4];
    int lane = threadIdx.x & 63, wid = threadIdx.x >> 6;
    if (lane == 0) smem[wid] = v;
    __syncthreads();
    float r = 0.f;
    if (threadIdx.x == 0) r = smem[0] + smem[1] + smem[2] + smem[3];
    return r;
}
// paired reduction; valid on tid 0 only
__device__ __forceinline__ float2 blockReduceSum2(float a, float b) {
    #pragma unroll
    for (int off = 32; off > 0; off >>= 1) {
        a += __shfl_down(a, off, 64);
        b += __shfl_down(b, off, 64);
    }
    __shared__ float sa[4], sb[4];
    int lane = threadIdx.x & 63, wid = threadIdx.x >> 6;
    if (lane == 0) { sa[wid] = a; sb[wid] = b; }
    __syncthreads();
    float ra = 0.f, rb = 0.f;
    if (threadIdx.x == 0) {
        ra = sa[0] + sa[1] + sa[2] + sa[3];
        rb = sb[0] + sb[1] + sb[2] + sb[3];
    }
    return make_float2(ra, rb);
}

// Persistent single-reduction CG + fused finalization. Plain launch
// (graph-capturable). Co-residency by capacity: waves_per_eu(2,2) -> 2
// blocks/CU, grid 512 = 2 x 256 CU (proven r5-r10: spin rounds complete).
// idx is SORTED, so block k-ranges own contiguous i-spans; the epilogue
// computes w/r/phi by a span walk with v still in registers.
__global__ __attribute__((amdgpu_flat_work_group_size(256, 256),
                          amdgpu_waves_per_eu(2, 2)))
void k_cg_pers(const int* __restrict__ idx, const float* __restrict__ u_all,
               const float* __restrict__ x, float* __restrict__ v_out,
               float* __restrict__ w_out, float* __restrict__ r_out,
               float* __restrict__ phi,
               unsigned long long* __restrict__ slotD,  // [2][nblk][4]
               unsigned long long* __restrict__ slotK,  // [2][2][nblk]
               unsigned long long* __restrict__ slotV,  // [nblk]
               unsigned long long* __restrict__ slotP,  // [nblk]
               int n, int K, int B, int nblk) {
    const int blk = blockIdx.x, tid = threadIdx.x;
    const int bpb = K / CHUNK;                  // 32
    const int b = blk / bpb, bbase = b * bpb;
    const bool first = (blk == bbase), last = (blk == bbase + bpb - 1);
    const int k0 = (blk - bbase) * CHUNK + tid * E;
    const int m = n - 1;
    const float* ub = u_all + (size_t)b * m;
    const float* xb = x + (size_t)b * n;

    // ---- init: dg, cl, r0 in registers ----
    int jj[E + 2];
    {
        const int4* ip = reinterpret_cast<const int4*>(idx + k0);  // k0 % 16 == 0
        #pragma unroll
        for (int q4 = 0; q4 < E / 4; ++q4) {
            int4 t = ip[q4];
            jj[1 + 4 * q4] = t.x; jj[2 + 4 * q4] = t.y;
            jj[3 + 4 * q4] = t.z; jj[4 + 4 * q4] = t.w;
        }
        jj[0]     = (k0 > 0)      ? idx[k0 - 1] : -1000000;
        jj[E + 1] = (k0 + E < K)  ? idx[k0 + E] : -1000000;
    }
    float vv[E], r[E], p[E], kp[E], dgr[E], clr[E + 1];
    float s0 = 0.f;
    float prev_wr = 0.f;
    #pragma unroll
    for (int q = 0; q < E; ++q) {
        int j = jj[q + 1];
        bool la = (jj[q] == j - 1);
        bool ra = (jj[q + 2] == j + 1);
        float wl = 0.f, wr = 0.f;
        if (j >= 1) {
            if (q > 0 && la) wl = prev_wr;                 // share neighbor's w^2
            else { float w = sp_w(ub[j - 1]); wl = w * w; }
        }
        if (j <= n - 2) { float w = sp_w(ub[j]); wr = w * w; }
        prev_wr = wr;
        float rhs = 0.f;
        if (j >= 1 && !la)     rhs += wl * nn(xb[j - 1]);
        if (j <= n - 2 && !ra) rhs += wr * nn(xb[j + 1]);
        vv[q] = 0.f; r[q] = rhs; p[q] = 0.f; kp[q] = 0.f;
        dgr[q] = wl + wr;
        clr[q] = la ? wl : 0.f;
        s0 += rhs * rhs;
    }
    {
        float cl8 = 0.f;
        int j8 = jj[E + 1];
        if ((k0 + E) < K && jj[E] == j8 - 1) { float w = sp_w(ub[j8 - 1]); cl8 = w * w; }
        clr[E] = cl8;
    }
    // publish initial r-edges (tag 1, parity-1 K slots)
    if (tid == 0)
        sys_st64(&slotK[1 * 2 * nblk + 0 * nblk + blk], mkword(1u, r[0]));
    if (tid == CGBLK - 1)
        sys_st64(&slotK[1 * 2 * nblk + 1 * nblk + blk], mkword(1u, r[E - 1]));

    float s0b = blockReduceSum(s0);   // tid0; published with round 0

    __shared__ float sLa[CGBLK], sRa[CGBLK];
    __shared__ float sm[3];           // D1, D2, RS0

    float rs = 0.f, beta = 0.f;
    float r_nbL = 0.f, p_nbL = 0.f;   // live in tid 0
    float r_nbR = 0.f, p_nbR = 0.f;   // live in tid 255

    for (int it = 0; it < MAX_ITER; ++it) {
        const unsigned G = (unsigned)(it + 2);
        const int par = it & 1;
        if (it == 0) {   // fetch neighbor r0 edges (self-tagged)
            if (tid == 0 && !first) {
                unsigned long long v0 = poll_tag(&slotK[1 * 2 * nblk + 1 * nblk + (blk - 1)], 1u);
                r_nbL = payload(v0);
            }
            if (tid == CGBLK - 1 && !last) {
                unsigned long long v0 = poll_tag(&slotK[1 * 2 * nblk + 0 * nblk + (blk + 1)], 1u);
                r_nbR = payload(v0);
            }
        }
        // p update (beta=0 at it=0) + bitwise neighbor mirror
        #pragma unroll
        for (int q = 0; q < E; ++q) p[q] = r[q] + beta * p[q];
        if (tid == 0)         p_nbL = r_nbL + beta * p_nbL;
        if (tid == CGBLK - 1) p_nbR = r_nbR + beta * p_nbR;
        sLa[tid] = p[0]; sRa[tid] = p[E - 1];
        __syncthreads();
        float pl = (tid > 0) ? sRa[tid - 1] : (first ? 0.f : p_nbL);
        float pr = (tid < CGBLK - 1) ? sLa[tid + 1] : (last ? 0.f : p_nbR);
        float d1 = 0.f, d2 = 0.f;
        #pragma unroll
        for (int q = 0; q < E; ++q) {
            float pm = (q == 0) ? pl : p[q - 1];
            float pp = (q == E - 1) ? pr : p[q + 1];
            kp[q] = dgr[q] * p[q] - clr[q] * pm - clr[q + 1] * pp;
            d1 += p[q] * kp[q];
            d2 += kp[q] * kp[q];
        }
        // publish Kp edges early (gen-tagged, parity-buffered)
        if (tid == 0)
            sys_st64(&slotK[par * 2 * nblk + 0 * nblk + blk], mkword(G, kp[0]));
        if (tid == CGBLK - 1)
            sys_st64(&slotK[par * 2 * nblk + 1 * nblk + blk], mkword(G, kp[E - 1]));
        float2 db = blockReduceSum2(d1, d2);
        if (tid == 0) {
            unsigned long long* base = &slotD[((size_t)par * nblk + blk) * 4];
            sys_st64(base + 0, mkword(G, db.x));
            sys_st64(base + 1, mkword(G, db.y));
            if (it == 0) sys_st64(base + 2, mkword(G, s0b));
        }
        // ---- all-to-all poll: one fabric hop ----
        float kpnbl = 0.f, kpnbr = 0.f;
        {
            int lane = tid & 63, wid = tid >> 6;
            if (wid == 0) {
                int which = lane >> 5;              // 0:d1  1:d2
                int li = lane & 31;
                float pv = 0.f;
                if (li < bpb) {
                    unsigned long long v0 =
                        poll_tag(&slotD[((size_t)par * nblk + (bbase + li)) * 4 + which], G);
                    pv = payload(v0);
                }
                #pragma unroll
                for (int off = 16; off > 0; off >>= 1) pv += __shfl_down(pv, off, 32);
                if (lane == 0)  sm[0] = pv;
                if (lane == 32) sm[1] = pv;
            } else if (wid == 1 && it == 0 && lane < 32) {
                float pv = 0.f;
                if (lane < bpb) {
                    unsigned long long v0 =
                        poll_tag(&slotD[((size_t)0 * nblk + (bbase + lane)) * 4 + 2], 2u);
                    pv = payload(v0);
                }
                #pragma unroll
                for (int off = 16; off > 0; off >>= 1) pv += __shfl_down(pv, off, 32);
                if (lane == 0) sm[2] = pv;
            }
            if (tid == 0 && !first) {
                unsigned long long v0 = poll_tag(&slotK[par * 2 * nblk + 1 * nblk + (blk - 1)], G);
                kpnbl = payload(v0);
            }
            if (tid == CGBLK - 1 && !last) {
                unsigned long long v0 = poll_tag(&slotK[par * 2 * nblk + 0 * nblk + (blk + 1)], G);
                kpnbr = payload(v0);
            }
        }
        __syncthreads();
        float D1 = sm[0], D2 = sm[1];
        if (it == 0) rs = sm[2];
        float alpha = rs / (D1 + 1e-30f);
        float rs_new = fmaxf(alpha * alpha * D2 - rs, 0.f);
        #pragma unroll
        for (int q = 0; q < E; ++q) {
            vv[q] += alpha * p[q];
            r[q]  -= alpha * kp[q];
        }
        if (tid == 0 && !first)        r_nbL -= alpha * kpnbl;
        if (tid == CGBLK - 1 && !last) r_nbR -= alpha * kpnbr;
        beta = rs_new / (rs + 1e-30f);
        rs = rs_new;
    }

    // ---- v writeout ----
    float* vb = v_out + (size_t)b * K + (size_t)(blk - bbase) * CHUNK + (size_t)tid * E;
    #pragma unroll
    for (int q4 = 0; q4 < E / 4; ++q4)
        reinterpret_cast<float4*>(vb)[q4] =
            make_float4(vv[4 * q4], vv[4 * q4 + 1], vv[4 * q4 + 2], vv[4 * q4 + 3]);

    // ---- fused finalization: span walk over i-space (idx sorted) ----
    const unsigned FG = (unsigned)(MAX_ITER + 2);   // 22
    if (tid == 0) sys_st64(&slotV[blk], mkword(FG, vv[0]));
    sLa[tid] = vv[0];        // safe: all threads passed the loop's last barrier
    __syncthreads();
    float v_next = 0.f;
    if (tid < CGBLK - 1)      v_next = sLa[tid + 1];
    else if (!last)           v_next = payload(poll_tag(&slotV[blk + 1], FG));

    int jl[E + 1];
    {
        const int4* ip = reinterpret_cast<const int4*>(idx + k0);
        #pragma unroll
        for (int q4 = 0; q4 < E / 4; ++q4) {
            int4 t = ip[q4];
            jl[4 * q4] = t.x; jl[4 * q4 + 1] = t.y;
            jl[4 * q4 + 2] = t.z; jl[4 * q4 + 3] = t.w;
        }
        jl[E] = (k0 + E < K) ? idx[k0 + E] : n;
    }
    const bool first_thread = first && (tid == 0);
    const bool last_thread  = last && (tid == CGBLK - 1);
    int j_lo = first_thread ? 0 : jl[0];
    int j_hi = last_thread ? n : jl[E];

    float* wb = w_out + (size_t)b * m;
    float* rb = r_out + (size_t)b * m;
    float phi_acc = 0.f;
    int kptr = 0;
    int i = j_lo;
    float s_cur;
    if (kptr < E && i == jl[kptr]) { s_cur = vv[kptr]; ++kptr; }
    else s_cur = nn(xb[i]);
    while (i < j_hi) {
        int ip = i + 1;
        float s_next;
        if (ip == j_hi) s_next = v_next;   // next thread's/block's first unknown (or i==m, unused)
        else if (kptr < E && ip == jl[kptr]) { s_next = vv[kptr]; ++kptr; }
        else s_next = nn(xb[ip]);
        if (i < m) {
            float wv = sp_w(ub[i]);
            float rv = s_next - s_cur;
            wb[i] = wv;
            rb[i] = rv;
            phi_acc += wv * wv * rv * rv;
        }
        s_cur = s_next;
        i = ip;
    }
    // phi: one more tagged all-to-all round; batch leader is single writer
    float pblk = blockReduceSum(phi_acc);
    if (tid == 0) sys_st64(&slotP[blk], mkword(FG, pblk));
    if (first) {
        int lane = tid & 63, wid = tid >> 6;
        if (wid == 0) {
            float pv = 0.f;
            if (lane < bpb) pv = payload(poll_tag(&slotP[bbase + lane], FG));
            #pragma unroll
            for (int off = 16; off > 0; off >>= 1) pv += __shfl_down(pv, off, 32);
            if (lane == 0) phi[b] = pv;
        }
    }
}

extern "C" void kernel_launch(void* const* d_in, const int* in_sizes, int n_in,
                              void* d_out, int out_size, void* d_ws, size_t ws_size,
                              hipStream_t stream) {
    const float* u  = (const float*)d_in[0];  // [B, n-1]
    const float* x  = (const float*)d_in[1];  // [B, n]
    const int* idx  = (const int*)d_in[2];    // [K], sorted

    const int B = 16;
    const int n = in_sizes[1] / B;   // 262144
    const int m = n - 1;             // 262143
    const int K = in_sizes[2];       // 131072
    const int NK = B * K;            // 2097152
    const int GRID = NK / CHUNK;     // 512 blocks = 2 per CU

    float* out   = (float*)d_out;
    float* phi   = out;                         // [B]
    float* v_out = out + B;                     // [B,K]
    float* r_out = v_out + (size_t)B * K;       // [B,m]
    float* w_out = r_out + (size_t)B * m;       // [B,m]

    char* ws = (char*)d_ws;
    unsigned long long* slotD = (unsigned long long*)ws;  ws += sizeof(unsigned long long) * 2 * GRID * 4;
    unsigned long long* slotK = (unsigned long long*)ws;  ws += sizeof(unsigned long long) * 2 * 2 * GRID;
    unsigned long long* slotV = (unsigned long long*)ws;  ws += sizeof(unsigned long long) * GRID;
    unsigned long long* slotP = (unsigned long long*)ws;  ws += sizeof(unsigned long long) * GRID;

    // one contiguous slot region, zeroed per call (tags restart each replay)
    hipMemsetAsync(slotD, 0,
                   sizeof(unsigned long long) * (2 * GRID * 4 + 2 * 2 * GRID + 2 * GRID),
                   stream);

    k_cg_pers<<<GRID, CGBLK, 0, stream>>>(idx, u, x, v_out, w_out, r_out, phi,
                                          slotD, slotK, slotV, slotP,
                                          n, K, B, GRID);
}

// Round 12
// 157.455 us; speedup vs baseline: 1.8585x; 1.8585x over previous
//
#include <hip/hip_runtime.h>
#include <math.h>

#define MAX_ITER 20
#define EPS_W 1e-3f
#define CLAMP_MIN 1e-4f
#define CLAMP_MAX 1e4f

#define E 16
#define CGBLK 256
#define CHUNK (E * CGBLK)  // 4096 elems/block; bpb = K/CHUNK = 32
#define SPAN_MAX 9216      // block i-span bound (mean 8193, sd ~64; 16 sigma)

__device__ __forceinline__ float sp_w(float u) {
    float sp = fmaxf(u, 0.f) + log1pf(expf(-fabsf(u)));
    float w = sp + EPS_W;
    return fminf(fmaxf(w, CLAMP_MIN), CLAMP_MAX);
}
__device__ __forceinline__ float nn(float x) { return (x == x) ? x : 0.f; }

// SYSTEM-scope relaxed atomics: cache-bypassing, coherence-point direct.
// (Measured r6->r7: poll rounds 21us -> 3.4us.)
__device__ __forceinline__ unsigned long long sys_ld64(const unsigned long long* p) {
    return __hip_atomic_load(p, __ATOMIC_RELAXED, __HIP_MEMORY_SCOPE_SYSTEM);
}
__device__ __forceinline__ unsigned long long sys_ld64_acq(const unsigned long long* p) {
    return __hip_atomic_load(p, __ATOMIC_ACQUIRE, __HIP_MEMORY_SCOPE_SYSTEM);
}
__device__ __forceinline__ void sys_st64(unsigned long long* p, unsigned long long v) {
    __hip_atomic_store(p, v, __ATOMIC_RELAXED, __HIP_MEMORY_SCOPE_SYSTEM);
}
__device__ __forceinline__ unsigned long long poll_tag(const unsigned long long* p, unsigned gen) {
    unsigned long long v; int s = 0;
    for (;;) {
        v = sys_ld64(p);
        if ((unsigned)(v >> 32) >= gen) return v;
        if ((++s & 63) == 0) {               // livelock insurance only
            v = sys_ld64_acq(p);
            if ((unsigned)(v >> 32) >= gen) return v;
        }
        __builtin_amdgcn_s_sleep(1);
    }
}
__device__ __forceinline__ unsigned long long mkword(unsigned gen, float f) {
    return ((unsigned long long)gen << 32) | (unsigned long long)__float_as_uint(f);
}
__device__ __forceinline__ float payload(unsigned long long v) {
    return __uint_as_float((unsigned)v);
}

// valid on tid 0 only; block = 256 threads (4 waves)
__device__ __forceinline__ float blockReduceSum(float v) {
    #pragma unroll
    for (int off = 32; off > 0; off >>= 1) v += __shfl_down(v, off, 64);
    __shared__ float smem[4];
    int lane = threadIdx.x & 63, wid = threadIdx.x >> 6;
    if (lane == 0) smem[wid] = v;
    __syncthreads();
    float r = 0.f;
    if (threadIdx.x == 0) r = smem[0] + smem[1] + smem[2] + smem[3];
    return r;
}
// paired reduction; valid on tid 0 only
__device__ __forceinline__ float2 blockReduceSum2(float a, float b) {
    #pragma unroll
    for (int off = 32; off > 0; off >>= 1) {
        a += __shfl_down(a, off, 64);
        b += __shfl_down(b, off, 64);
    }
    __shared__ float sa[4], sb[4];
    int lane = threadIdx.x & 63, wid = threadIdx.x >> 6;
    if (lane == 0) { sa[wid] = a; sb[wid] = b; }
    __syncthreads();
    float ra = 0.f, rb = 0.f;
    if (threadIdx.x == 0) {
        ra = sa[0] + sa[1] + sa[2] + sa[3];
        rb = sb[0] + sb[1] + sb[2] + sb[3];
    }
    return make_float2(ra, rb);
}

// Persistent single-reduction CG + fully fused pre/post. Plain launch
// (graph-capturable). Co-residency by capacity: waves_per_eu(2,2) + LDS
// 75.8KB/block -> exactly 2 blocks/CU, grid 512 = 2 x 256 CU (spin rounds
// proven r5-r10). idx SORTED -> block i-spans contiguous (~8193 +- 64):
// staged in LDS for coalesced init gathers and epilogue walk (r11's fused
// walk was correct but divergent-global -> 16x overfetch; LDS fixes it).
__global__ __attribute__((amdgpu_flat_work_group_size(256, 256),
                          amdgpu_waves_per_eu(2, 2)))
void k_cg_pers(const int* __restrict__ idx, const float* __restrict__ u_all,
               const float* __restrict__ x, float* __restrict__ v_out,
               float* __restrict__ w_out, float* __restrict__ r_out,
               float* __restrict__ phi,
               unsigned long long* __restrict__ slotD,  // [2][nblk][4]
               unsigned long long* __restrict__ slotK,  // [2][2][nblk]
               unsigned long long* __restrict__ slotV,  // [nblk]
               unsigned long long* __restrict__ slotP,  // [nblk]
               int n, int K, int B, int nblk) {
    const int blk = blockIdx.x, tid = threadIdx.x;
    const int bpb = K / CHUNK;                  // 32
    const int b = blk / bpb, bbase = b * bpb;
    const bool first = (blk == bbase), last = (blk == bbase + bpb - 1);
    const int k0 = (blk - bbase) * CHUNK + tid * E;
    const int m = n - 1;
    const float* ub = u_all + (size_t)b * m;
    const float* xb = x + (size_t)b * n;

    __shared__ float sU[SPAN_MAX], sX[SPAN_MAX];
    __shared__ float sLa[CGBLK], sRa[CGBLK];
    __shared__ float sm[3];           // D1, D2, RS0
    __shared__ int sInfo[4];          // lo, len, jloB, jhiB

    // ---- block i-span + LDS staging (coalesced) ----
    if (tid == 0) {
        int kblk = (blk - bbase) * CHUNK;
        int jlo = first ? 0 : idx[kblk];
        int jhi = last ? n : idx[kblk + CHUNK];
        int lo_ = (jlo > 0) ? jlo - 1 : 0;
        sInfo[0] = lo_;
        sInfo[1] = jhi - lo_;
        sInfo[2] = jlo;
        sInfo[3] = jhi;
    }
    __syncthreads();
    const int lo = sInfo[0], len = sInfo[1], jloB = sInfo[2], jhiB = sInfo[3];
    const bool staged = (len <= SPAN_MAX);
    if (staged) {
        for (int t = tid; t < len; t += CGBLK) {
            int i = lo + t;
            sX[t] = xb[i];
            sU[t] = (i < m) ? ub[i] : 0.f;
        }
        __syncthreads();
    }
    auto LX = [&](int i) -> float { return staged ? sX[i - lo] : xb[i]; };
    auto LU = [&](int i) -> float { return staged ? sU[i - lo] : ub[i]; };

    // ---- init: dg, cl, r0 in registers ----
    int jj[E + 2];
    {
        const int4* ip = reinterpret_cast<const int4*>(idx + k0);  // k0 % 16 == 0
        #pragma unroll
        for (int q4 = 0; q4 < E / 4; ++q4) {
            int4 t = ip[q4];
            jj[1 + 4 * q4] = t.x; jj[2 + 4 * q4] = t.y;
            jj[3 + 4 * q4] = t.z; jj[4 + 4 * q4] = t.w;
        }
        jj[0]     = (k0 > 0)      ? idx[k0 - 1] : -1000000;
        jj[E + 1] = (k0 + E < K)  ? idx[k0 + E] : -1000000;
    }
    float vv[E], r[E], p[E], kp[E], dgr[E], clr[E + 1];
    float s0 = 0.f;
    float prev_wr = 0.f;
    #pragma unroll
    for (int q = 0; q < E; ++q) {
        int j = jj[q + 1];
        bool la = (jj[q] == j - 1);
        bool ra = (jj[q + 2] == j + 1);
        float wl = 0.f, wr = 0.f;
        if (j >= 1) {
            if (q > 0 && la) wl = prev_wr;                 // share neighbor's w^2
            else { float w = sp_w(LU(j - 1)); wl = w * w; }
        }
        if (j <= n - 2) { float w = sp_w(LU(j)); wr = w * w; }
        prev_wr = wr;
        float rhs = 0.f;
        if (j >= 1 && !la)     rhs += wl * nn(LX(j - 1));
        if (j <= n - 2 && !ra) rhs += wr * nn(LX(j + 1));
        vv[q] = 0.f; r[q] = rhs; p[q] = 0.f; kp[q] = 0.f;
        dgr[q] = wl + wr;
        clr[q] = la ? wl : 0.f;
        s0 += rhs * rhs;
    }
    {
        float cl8 = 0.f;
        int j8 = jj[E + 1];
        if ((k0 + E) < K && jj[E] == j8 - 1) { float w = sp_w(LU(j8 - 1)); cl8 = w * w; }
        clr[E] = cl8;
    }
    // publish initial r-edges (tag 1, parity-1 K slots)
    if (tid == 0)
        sys_st64(&slotK[1 * 2 * nblk + 0 * nblk + blk], mkword(1u, r[0]));
    if (tid == CGBLK - 1)
        sys_st64(&slotK[1 * 2 * nblk + 1 * nblk + blk], mkword(1u, r[E - 1]));

    float s0b = blockReduceSum(s0);   // tid0; published with round 0

    float rs = 0.f, beta = 0.f;
    float r_nbL = 0.f, p_nbL = 0.f;   // live in tid 0
    float r_nbR = 0.f, p_nbR = 0.f;   // live in tid 255

    for (int it = 0; it < MAX_ITER; ++it) {
        const unsigned G = (unsigned)(it + 2);
        const int par = it & 1;
        if (it == 0) {   // fetch neighbor r0 edges (self-tagged)
            if (tid == 0 && !first) {
                unsigned long long v0 = poll_tag(&slotK[1 * 2 * nblk + 1 * nblk + (blk - 1)], 1u);
                r_nbL = payload(v0);
            }
            if (tid == CGBLK - 1 && !last) {
                unsigned long long v0 = poll_tag(&slotK[1 * 2 * nblk + 0 * nblk + (blk + 1)], 1u);
                r_nbR = payload(v0);
            }
        }
        // p update (beta=0 at it=0) + bitwise neighbor mirror
        #pragma unroll
        for (int q = 0; q < E; ++q) p[q] = r[q] + beta * p[q];
        if (tid == 0)         p_nbL = r_nbL + beta * p_nbL;
        if (tid == CGBLK - 1) p_nbR = r_nbR + beta * p_nbR;
        sLa[tid] = p[0]; sRa[tid] = p[E - 1];
        __syncthreads();
        float pl = (tid > 0) ? sRa[tid - 1] : (first ? 0.f : p_nbL);
        float pr = (tid < CGBLK - 1) ? sLa[tid + 1] : (last ? 0.f : p_nbR);
        float d1 = 0.f, d2 = 0.f;
        #pragma unroll
        for (int q = 0; q < E; ++q) {
            float pm = (q == 0) ? pl : p[q - 1];
            float pp = (q == E - 1) ? pr : p[q + 1];
            kp[q] = dgr[q] * p[q] - clr[q] * pm - clr[q + 1] * pp;
            d1 += p[q] * kp[q];
            d2 += kp[q] * kp[q];
        }
        // publish Kp edges early (gen-tagged, parity-buffered)
        if (tid == 0)
            sys_st64(&slotK[par * 2 * nblk + 0 * nblk + blk], mkword(G, kp[0]));
        if (tid == CGBLK - 1)
            sys_st64(&slotK[par * 2 * nblk + 1 * nblk + blk], mkword(G, kp[E - 1]));
        float2 db = blockReduceSum2(d1, d2);
        if (tid == 0) {
            unsigned long long* base = &slotD[((size_t)par * nblk + blk) * 4];
            sys_st64(base + 0, mkword(G, db.x));
            sys_st64(base + 1, mkword(G, db.y));
            if (it == 0) sys_st64(base + 2, mkword(G, s0b));
        }
        // ---- all-to-all poll: one fabric hop ----
        float kpnbl = 0.f, kpnbr = 0.f;
        {
            int lane = tid & 63, wid = tid >> 6;
            if (wid == 0) {
                int which = lane >> 5;              // 0:d1  1:d2
                int li = lane & 31;
                float pv = 0.f;
                if (li < bpb) {
                    unsigned long long v0 =
                        poll_tag(&slotD[((size_t)par * nblk + (bbase + li)) * 4 + which], G);
                    pv = payload(v0);
                }
                #pragma unroll
                for (int off = 16; off > 0; off >>= 1) pv += __shfl_down(pv, off, 32);
                if (lane == 0)  sm[0] = pv;
                if (lane == 32) sm[1] = pv;
            } else if (wid == 1 && it == 0 && lane < 32) {
                float pv = 0.f;
                if (lane < bpb) {
                    unsigned long long v0 =
                        poll_tag(&slotD[((size_t)0 * nblk + (bbase + lane)) * 4 + 2], 2u);
                    pv = payload(v0);
                }
                #pragma unroll
                for (int off = 16; off > 0; off >>= 1) pv += __shfl_down(pv, off, 32);
                if (lane == 0) sm[2] = pv;
            }
            if (tid == 0 && !first) {
                unsigned long long v0 = poll_tag(&slotK[par * 2 * nblk + 1 * nblk + (blk - 1)], G);
                kpnbl = payload(v0);
            }
            if (tid == CGBLK - 1 && !last) {
                unsigned long long v0 = poll_tag(&slotK[par * 2 * nblk + 0 * nblk + (blk + 1)], G);
                kpnbr = payload(v0);
            }
        }
        __syncthreads();
        float D1 = sm[0], D2 = sm[1];
        if (it == 0) rs = sm[2];
        float alpha = rs / (D1 + 1e-30f);
        float rs_new = fmaxf(alpha * alpha * D2 - rs, 0.f);
        #pragma unroll
        for (int q = 0; q < E; ++q) {
            vv[q] += alpha * p[q];
            r[q]  -= alpha * kp[q];
        }
        if (tid == 0 && !first)        r_nbL -= alpha * kpnbl;
        if (tid == CGBLK - 1 && !last) r_nbR -= alpha * kpnbr;
        beta = rs_new / (rs + 1e-30f);
        rs = rs_new;
    }

    // ---- v writeout (coalesced) ----
    float* vb = v_out + (size_t)b * K + (size_t)(blk - bbase) * CHUNK + (size_t)tid * E;
    #pragma unroll
    for (int q4 = 0; q4 < E / 4; ++q4)
        reinterpret_cast<float4*>(vb)[q4] =
            make_float4(vv[4 * q4], vv[4 * q4 + 1], vv[4 * q4 + 2], vv[4 * q4 + 3]);

    // ---- fused finalization: span walk (LDS-backed), then coalesced writeout ----
    const unsigned FG = (unsigned)(MAX_ITER + 2);   // 22
    if (tid == 0) sys_st64(&slotV[blk], mkword(FG, vv[0]));
    sLa[tid] = vv[0];        // all threads past the loop's final barrier
    __syncthreads();
    float v_next = 0.f;
    if (tid < CGBLK - 1)      v_next = sLa[tid + 1];
    else if (!last)           v_next = payload(poll_tag(&slotV[blk + 1], FG));

    int jl[E + 1];
    {
        const int4* ip = reinterpret_cast<const int4*>(idx + k0);
        #pragma unroll
        for (int q4 = 0; q4 < E / 4; ++q4) {
            int4 t = ip[q4];
            jl[4 * q4] = t.x; jl[4 * q4 + 1] = t.y;
            jl[4 * q4 + 2] = t.z; jl[4 * q4 + 3] = t.w;
        }
        jl[E] = (k0 + E < K) ? idx[k0 + E] : n;
    }
    const bool first_thread = first && (tid == 0);
    const bool last_thread  = last && (tid == CGBLK - 1);
    int j_lo = first_thread ? 0 : jl[0];
    int j_hi = last_thread ? n : jl[E];

    float* wb = w_out + (size_t)b * m;
    float* rb = r_out + (size_t)b * m;
    float phi_acc = 0.f;
    {
        int kptr = 0;
        int i = j_lo;
        float s_cur;
        if (kptr < E && i == jl[kptr]) { s_cur = vv[kptr]; ++kptr; }
        else s_cur = nn(LX(i));
        while (i < j_hi) {
            int ip = i + 1;
            float s_next;
            if (ip == j_hi) s_next = v_next;
            else if (kptr < E && ip == jl[kptr]) { s_next = vv[kptr]; ++kptr; }
            else s_next = nn(LX(ip));
            if (i < m) {
                float wv = sp_w(LU(i));
                float rv = s_next - s_cur;
                float acc = wv * wv * rv * rv;
                if (staged) { sU[i - lo] = wv; sX[i - lo] = rv; }
                else        { wb[i] = wv;      rb[i] = rv; }
                phi_acc += acc;
            }
            s_cur = s_next;
            i = ip;
        }
    }
    if (staged) {
        __syncthreads();   // all walks complete before cooperative writeout
        int wrLo = first ? 0 : jloB;
        int wrHi = (jhiB < m) ? jhiB : m;
        for (int t = tid; t < len; t += CGBLK) {
            int i = lo + t;
            if (i >= wrLo && i < wrHi) { wb[i] = sU[t]; rb[i] = sX[t]; }
        }
    }
    // phi: one tagged all-to-all round; batch leader is single writer
    float pblk = blockReduceSum(phi_acc);
    if (tid == 0) sys_st64(&slotP[blk], mkword(FG, pblk));
    if (first) {
        int lane = tid & 63, wid = tid >> 6;
        if (wid == 0) {
            float pv = 0.f;
            if (lane < bpb) pv = payload(poll_tag(&slotP[bbase + lane], FG));
            #pragma unroll
            for (int off = 16; off > 0; off >>= 1) pv += __shfl_down(pv, off, 32);
            if (lane == 0) phi[b] = pv;
        }
    }
}

extern "C" void kernel_launch(void* const* d_in, const int* in_sizes, int n_in,
                              void* d_out, int out_size, void* d_ws, size_t ws_size,
                              hipStream_t stream) {
    const float* u  = (const float*)d_in[0];  // [B, n-1]
    const float* x  = (const float*)d_in[1];  // [B, n]
    const int* idx  = (const int*)d_in[2];    // [K], sorted

    const int B = 16;
    const int n = in_sizes[1] / B;   // 262144
    const int m = n - 1;             // 262143
    const int K = in_sizes[2];       // 131072
    const int NK = B * K;            // 2097152
    const int GRID = NK / CHUNK;     // 512 blocks = 2 per CU

    float* out   = (float*)d_out;
    float* phi   = out;                         // [B]
    float* v_out = out + B;                     // [B,K]
    float* r_out = v_out + (size_t)B * K;       // [B,m]
    float* w_out = r_out + (size_t)B * m;       // [B,m]

    char* ws = (char*)d_ws;
    unsigned long long* slotD = (unsigned long long*)ws;  ws += sizeof(unsigned long long) * 2 * GRID * 4;
    unsigned long long* slotK = (unsigned long long*)ws;  ws += sizeof(unsigned long long) * 2 * 2 * GRID;
    unsigned long long* slotV = (unsigned long long*)ws;  ws += sizeof(unsigned long long) * GRID;
    unsigned long long* slotP = (unsigned long long*)ws;  ws += sizeof(unsigned long long) * GRID;

    // one contiguous slot region, zeroed per call (tags restart each replay)
    hipMemsetAsync(slotD, 0,
                   sizeof(unsigned long long) * (2 * GRID * 4 + 2 * 2 * GRID + 2 * GRID),
                   stream);

    k_cg_pers<<<GRID, CGBLK, 0, stream>>>(idx, u, x, v_out, w_out, r_out, phi,
                                          slotD, slotK, slotV, slotP,
                                          n, K, B, GRID);
}

// Round 13
// 111.116 us; speedup vs baseline: 2.6336x; 1.4170x over previous
//
#include <hip/hip_runtime.h>
#include <math.h>

#define MAX_ITER 20
#define EPS_W 1e-3f
#define CLAMP_MIN 1e-4f
#define CLAMP_MAX 1e4f

#define E 16
#define CGBLK 256
#define CHUNK (E * CGBLK)  // 4096 elems/block; bpb = K/CHUNK = 32
#define SPAN_MAX 9216      // block i-span bound (mean 8193, sd ~64; 16 sigma)
#define PAD(t) ((t) + ((t) >> 5))   // +1-per-32 padding: kills stride-32 bank conflicts
#define SPAN_PAD (SPAN_MAX + SPAN_MAX / 32)  // 9504

__device__ __forceinline__ float sp_w(float u) {
    float sp = fmaxf(u, 0.f) + log1pf(expf(-fabsf(u)));
    float w = sp + EPS_W;
    return fminf(fmaxf(w, CLAMP_MIN), CLAMP_MAX);
}
__device__ __forceinline__ float nn(float x) { return (x == x) ? x : 0.f; }

// SYSTEM-scope relaxed atomics: cache-bypassing, coherence-point direct.
// (Measured r6->r7: poll rounds 21us -> 3.4us.)
__device__ __forceinline__ unsigned long long sys_ld64(const unsigned long long* p) {
    return __hip_atomic_load(p, __ATOMIC_RELAXED, __HIP_MEMORY_SCOPE_SYSTEM);
}
__device__ __forceinline__ unsigned long long sys_ld64_acq(const unsigned long long* p) {
    return __hip_atomic_load(p, __ATOMIC_ACQUIRE, __HIP_MEMORY_SCOPE_SYSTEM);
}
__device__ __forceinline__ void sys_st64(unsigned long long* p, unsigned long long v) {
    __hip_atomic_store(p, v, __ATOMIC_RELAXED, __HIP_MEMORY_SCOPE_SYSTEM);
}
__device__ __forceinline__ unsigned long long poll_tag(const unsigned long long* p, unsigned gen) {
    unsigned long long v; int s = 0;
    for (;;) {
        v = sys_ld64(p);
        if ((unsigned)(v >> 32) >= gen) return v;
        if ((++s & 63) == 0) {               // livelock insurance only
            v = sys_ld64_acq(p);
            if ((unsigned)(v >> 32) >= gen) return v;
        }
        __builtin_amdgcn_s_sleep(1);
    }
}
__device__ __forceinline__ unsigned long long mkword(unsigned gen, float f) {
    return ((unsigned long long)gen << 32) | (unsigned long long)__float_as_uint(f);
}
__device__ __forceinline__ float payload(unsigned long long v) {
    return __uint_as_float((unsigned)v);
}

// valid on tid 0 only; block = 256 threads (4 waves)
__device__ __forceinline__ float blockReduceSum(float v) {
    #pragma unroll
    for (int off = 32; off > 0; off >>= 1) v += __shfl_down(v, off, 64);
    __shared__ float smem[4];
    int lane = threadIdx.x & 63, wid = threadIdx.x >> 6;
    if (lane == 0) smem[wid] = v;
    __syncthreads();
    float r = 0.f;
    if (threadIdx.x == 0) r = smem[0] + smem[1] + smem[2] + smem[3];
    return r;
}
// paired reduction; valid on tid 0 only
__device__ __forceinline__ float2 blockReduceSum2(float a, float b) {
    #pragma unroll
    for (int off = 32; off > 0; off >>= 1) {
        a += __shfl_down(a, off, 64);
        b += __shfl_down(b, off, 64);
    }
    __shared__ float sa[4], sb[4];
    int lane = threadIdx.x & 63, wid = threadIdx.x >> 6;
    if (lane == 0) { sa[wid] = a; sb[wid] = b; }
    __syncthreads();
    float ra = 0.f, rb = 0.f;
    if (threadIdx.x == 0) {
        ra = sa[0] + sa[1] + sa[2] + sa[3];
        rb = sb[0] + sb[1] + sb[2] + sb[3];
    }
    return make_float2(ra, rb);
}

// Persistent single-reduction CG + fused pre/post, all LDS accesses padded
// conflict-free. Plain launch (graph-capturable). Co-residency by capacity:
// waves_per_eu(2,2) + 78KB LDS -> exactly 2 blocks/CU, grid 512 = 2 x 256 CU.
__global__ __attribute__((amdgpu_flat_work_group_size(256, 256),
                          amdgpu_waves_per_eu(2, 2)))
void k_cg_pers(const int* __restrict__ idx, const float* __restrict__ u_all,
               const float* __restrict__ x, float* __restrict__ v_out,
               float* __restrict__ w_out, float* __restrict__ r_out,
               float* __restrict__ phi,
               unsigned long long* __restrict__ slotD,  // [2][nblk][4]
               unsigned long long* __restrict__ slotK,  // [2][2][nblk]
               unsigned long long* __restrict__ slotV,  // [nblk]
               unsigned long long* __restrict__ slotP,  // [nblk]
               int n, int K, int B, int nblk) {
    const int blk = blockIdx.x, tid = threadIdx.x;
    const int bpb = K / CHUNK;                  // 32
    const int b = blk / bpb, bbase = b * bpb;
    const bool first = (blk == bbase), last = (blk == bbase + bpb - 1);
    const int k0 = (blk - bbase) * CHUNK + tid * E;
    const int m = n - 1;
    const float* ub = u_all + (size_t)b * m;
    const float* xb = x + (size_t)b * n;

    __shared__ float sX[SPAN_PAD], sW[SPAN_PAD];
    __shared__ float sLa[CGBLK], sRa[CGBLK];
    __shared__ float sm[3];           // D1, D2, RS0
    __shared__ int sInfo[4];          // lo, len, jloB, jhiB
    __shared__ float sVN;             // next block's first v

    // ---- block i-span + coalesced staging: sX = nn(x), sW = sp_w(u) ----
    if (tid == 0) {
        int kblk = (blk - bbase) * CHUNK;
        int jlo = first ? 0 : idx[kblk];
        int jhi = last ? n : idx[kblk + CHUNK];
        int lo_ = (jlo > 0) ? jlo - 1 : 0;
        sInfo[0] = lo_;
        sInfo[1] = jhi - lo_;
        sInfo[2] = jlo;
        sInfo[3] = jhi;
    }
    __syncthreads();
    const int lo = sInfo[0], len = sInfo[1], jloB = sInfo[2], jhiB = sInfo[3];
    const bool staged = (len <= SPAN_MAX);
    if (staged) {
        for (int t = tid; t < len; t += CGBLK) {
            int i = lo + t;
            sX[PAD(t)] = nn(xb[i]);
            sW[PAD(t)] = (i < m) ? sp_w(ub[i]) : 0.f;
        }
        __syncthreads();
    }
    auto LXn = [&](int i) -> float { return staged ? sX[PAD(i - lo)] : nn(xb[i]); };
    auto LW  = [&](int i) -> float { return staged ? sW[PAD(i - lo)] : sp_w(ub[i]); };

    // ---- init: dg, cl, r0 in registers (LDS gathers, conflict-free) ----
    int jj[E + 2];
    {
        const int4* ip = reinterpret_cast<const int4*>(idx + k0);  // k0 % 16 == 0
        #pragma unroll
        for (int q4 = 0; q4 < E / 4; ++q4) {
            int4 t = ip[q4];
            jj[1 + 4 * q4] = t.x; jj[2 + 4 * q4] = t.y;
            jj[3 + 4 * q4] = t.z; jj[4 + 4 * q4] = t.w;
        }
        jj[0]     = (k0 > 0)      ? idx[k0 - 1] : -1000000;
        jj[E + 1] = (k0 + E < K)  ? idx[k0 + E] : -1000000;
    }
    float vv[E], r[E], p[E], kp[E], dgr[E], clr[E + 1];
    float s0 = 0.f;
    #pragma unroll
    for (int q = 0; q < E; ++q) {
        int j = jj[q + 1];
        bool la = (jj[q] == j - 1);
        bool ra = (jj[q + 2] == j + 1);
        float wl = 0.f, wr = 0.f;
        if (j >= 1)     { float w = LW(j - 1); wl = w * w; }
        if (j <= n - 2) { float w = LW(j);     wr = w * w; }
        float rhs = 0.f;
        if (j >= 1 && !la)     rhs += wl * LXn(j - 1);
        if (j <= n - 2 && !ra) rhs += wr * LXn(j + 1);
        vv[q] = 0.f; r[q] = rhs; p[q] = 0.f; kp[q] = 0.f;
        dgr[q] = wl + wr;
        clr[q] = la ? wl : 0.f;
        s0 += rhs * rhs;
    }
    {
        float cl8 = 0.f;
        int j8 = jj[E + 1];
        if ((k0 + E) < K && jj[E] == j8 - 1) { float w = LW(j8 - 1); cl8 = w * w; }
        clr[E] = cl8;
    }
    // publish initial r-edges (tag 1, parity-1 K slots)
    if (tid == 0)
        sys_st64(&slotK[1 * 2 * nblk + 0 * nblk + blk], mkword(1u, r[0]));
    if (tid == CGBLK - 1)
        sys_st64(&slotK[1 * 2 * nblk + 1 * nblk + blk], mkword(1u, r[E - 1]));

    float s0b = blockReduceSum(s0);   // tid0; published with round 0

    float rs = 0.f, beta = 0.f;
    float r_nbL = 0.f, p_nbL = 0.f;   // live in tid 0
    float r_nbR = 0.f, p_nbR = 0.f;   // live in tid 255

    for (int it = 0; it < MAX_ITER; ++it) {
        const unsigned G = (unsigned)(it + 2);
        const int par = it & 1;
        if (it == 0) {   // fetch neighbor r0 edges (self-tagged)
            if (tid == 0 && !first) {
                unsigned long long v0 = poll_tag(&slotK[1 * 2 * nblk + 1 * nblk + (blk - 1)], 1u);
                r_nbL = payload(v0);
            }
            if (tid == CGBLK - 1 && !last) {
                unsigned long long v0 = poll_tag(&slotK[1 * 2 * nblk + 0 * nblk + (blk + 1)], 1u);
                r_nbR = payload(v0);
            }
        }
        // p update (beta=0 at it=0) + bitwise neighbor mirror
        #pragma unroll
        for (int q = 0; q < E; ++q) p[q] = r[q] + beta * p[q];
        if (tid == 0)         p_nbL = r_nbL + beta * p_nbL;
        if (tid == CGBLK - 1) p_nbR = r_nbR + beta * p_nbR;
        sLa[tid] = p[0]; sRa[tid] = p[E - 1];
        __syncthreads();
        float pl = (tid > 0) ? sRa[tid - 1] : (first ? 0.f : p_nbL);
        float pr = (tid < CGBLK - 1) ? sLa[tid + 1] : (last ? 0.f : p_nbR);
        float d1 = 0.f, d2 = 0.f;
        #pragma unroll
        for (int q = 0; q < E; ++q) {
            float pm = (q == 0) ? pl : p[q - 1];
            float pp = (q == E - 1) ? pr : p[q + 1];
            kp[q] = dgr[q] * p[q] - clr[q] * pm - clr[q + 1] * pp;
            d1 += p[q] * kp[q];
            d2 += kp[q] * kp[q];
        }
        // publish Kp edges early (gen-tagged, parity-buffered)
        if (tid == 0)
            sys_st64(&slotK[par * 2 * nblk + 0 * nblk + blk], mkword(G, kp[0]));
        if (tid == CGBLK - 1)
            sys_st64(&slotK[par * 2 * nblk + 1 * nblk + blk], mkword(G, kp[E - 1]));
        float2 db = blockReduceSum2(d1, d2);
        if (tid == 0) {
            unsigned long long* base = &slotD[((size_t)par * nblk + blk) * 4];
            sys_st64(base + 0, mkword(G, db.x));
            sys_st64(base + 1, mkword(G, db.y));
            if (it == 0) sys_st64(base + 2, mkword(G, s0b));
        }
        // ---- all-to-all poll: one fabric hop ----
        float kpnbl = 0.f, kpnbr = 0.f;
        {
            int lane = tid & 63, wid = tid >> 6;
            if (wid == 0) {
                int which = lane >> 5;              // 0:d1  1:d2
                int li = lane & 31;
                float pv = 0.f;
                if (li < bpb) {
                    unsigned long long v0 =
                        poll_tag(&slotD[((size_t)par * nblk + (bbase + li)) * 4 + which], G);
                    pv = payload(v0);
                }
                #pragma unroll
                for (int off = 16; off > 0; off >>= 1) pv += __shfl_down(pv, off, 32);
                if (lane == 0)  sm[0] = pv;
                if (lane == 32) sm[1] = pv;
            } else if (wid == 1 && it == 0 && lane < 32) {
                float pv = 0.f;
                if (lane < bpb) {
                    unsigned long long v0 =
                        poll_tag(&slotD[((size_t)0 * nblk + (bbase + lane)) * 4 + 2], 2u);
                    pv = payload(v0);
                }
                #pragma unroll
                for (int off = 16; off > 0; off >>= 1) pv += __shfl_down(pv, off, 32);
                if (lane == 0) sm[2] = pv;
            }
            if (tid == 0 && !first) {
                unsigned long long v0 = poll_tag(&slotK[par * 2 * nblk + 1 * nblk + (blk - 1)], G);
                kpnbl = payload(v0);
            }
            if (tid == CGBLK - 1 && !last) {
                unsigned long long v0 = poll_tag(&slotK[par * 2 * nblk + 0 * nblk + (blk + 1)], G);
                kpnbr = payload(v0);
            }
        }
        __syncthreads();
        float D1 = sm[0], D2 = sm[1];
        if (it == 0) rs = sm[2];
        float alpha = rs / (D1 + 1e-30f);
        float rs_new = fmaxf(alpha * alpha * D2 - rs, 0.f);
        #pragma unroll
        for (int q = 0; q < E; ++q) {
            vv[q] += alpha * p[q];
            r[q]  -= alpha * kp[q];
        }
        if (tid == 0 && !first)        r_nbL -= alpha * kpnbl;
        if (tid == CGBLK - 1 && !last) r_nbR -= alpha * kpnbr;
        beta = rs_new / (rs + 1e-30f);
        rs = rs_new;
    }

    // ---- publish v0 early; v writeout (coalesced) ----
    const unsigned FG = (unsigned)(MAX_ITER + 2);   // 22
    if (tid == 0) sys_st64(&slotV[blk], mkword(FG, vv[0]));
    float* vb = v_out + (size_t)b * K + (size_t)(blk - bbase) * CHUNK + (size_t)tid * E;
    #pragma unroll
    for (int q4 = 0; q4 < E / 4; ++q4)
        reinterpret_cast<float4*>(vb)[q4] =
            make_float4(vv[4 * q4], vv[4 * q4 + 1], vv[4 * q4 + 2], vv[4 * q4 + 3]);

    // reload idx window (init's jj may have been re-used by regalloc)
    int jl[E + 1];
    {
        const int4* ip = reinterpret_cast<const int4*>(idx + k0);
        #pragma unroll
        for (int q4 = 0; q4 < E / 4; ++q4) {
            int4 t = ip[q4];
            jl[4 * q4] = t.x; jl[4 * q4 + 1] = t.y;
            jl[4 * q4 + 2] = t.z; jl[4 * q4 + 3] = t.w;
        }
        jl[E] = (k0 + E < K) ? idx[k0 + E] : n;
    }

    float* wb = w_out + (size_t)b * m;
    float* rb = r_out + (size_t)b * m;
    float phi_acc = 0.f;

    if (staged) {
        // scatter register v into padded span (padding spreads the ~32-stride)
        if (tid == CGBLK - 1) sVN = last ? 0.f : payload(poll_tag(&slotV[blk + 1], FG));
        #pragma unroll
        for (int q = 0; q < E; ++q) sX[PAD(jl[q] - lo)] = vv[q];
        __syncthreads();
        // coalesced pass: r = D(s), w from sW, phi accumulate, coalesced stores
        int tLo = jloB - lo;
        int wrHi = (jhiB < m) ? jhiB : m;
        int tHi = wrHi - lo;
        float vnext = sVN;
        for (int t = tLo + tid; t < tHi; t += CGBLK) {
            int i = lo + t;
            float s_cur = sX[PAD(t)];
            float s_next = (i + 1 == jhiB) ? vnext : sX[PAD(t + 1)];
            float w = sW[PAD(t)];
            float rv = s_next - s_cur;
            wb[i] = w;
            rb[i] = rv;
            phi_acc += w * w * rv * rv;
        }
    } else {
        // fallback (len > SPAN_MAX, ~impossible): serial walk on global
        sLa[tid] = vv[0];
        __syncthreads();
        float v_next = 0.f;
        if (tid < CGBLK - 1)      v_next = sLa[tid + 1];
        else if (!last)           v_next = payload(poll_tag(&slotV[blk + 1], FG));
        const bool first_thread = first && (tid == 0);
        const bool last_thread  = last && (tid == CGBLK - 1);
        int j_lo = first_thread ? 0 : jl[0];
        int j_hi = last_thread ? n : jl[E];
        int kptr = 0;
        int i = j_lo;
        float s_cur;
        if (kptr < E && i == jl[kptr]) { s_cur = vv[kptr]; ++kptr; }
        else s_cur = nn(xb[i]);
        while (i < j_hi) {
            int ip = i + 1;
            float s_next;
            if (ip == j_hi) s_next = v_next;
            else if (kptr < E && ip == jl[kptr]) { s_next = vv[kptr]; ++kptr; }
            else s_next = nn(xb[ip]);
            if (i < m) {
                float wv = sp_w(ub[i]);
                float rv = s_next - s_cur;
                wb[i] = wv;
                rb[i] = rv;
                phi_acc += wv * wv * rv * rv;
            }
            s_cur = s_next;
            i = ip;
        }
    }

    // phi: one tagged all-to-all round; batch leader is single writer
    float pblk = blockReduceSum(phi_acc);
    if (tid == 0) sys_st64(&slotP[blk], mkword(FG, pblk));
    if (first) {
        int lane = tid & 63, wid = tid >> 6;
        if (wid == 0) {
            float pv = 0.f;
            if (lane < bpb) pv = payload(poll_tag(&slotP[bbase + lane], FG));
            #pragma unroll
            for (int off = 16; off > 0; off >>= 1) pv += __shfl_down(pv, off, 32);
            if (lane == 0) phi[b] = pv;
        }
    }
}

extern "C" void kernel_launch(void* const* d_in, const int* in_sizes, int n_in,
                              void* d_out, int out_size, void* d_ws, size_t ws_size,
                              hipStream_t stream) {
    const float* u  = (const float*)d_in[0];  // [B, n-1]
    const float* x  = (const float*)d_in[1];  // [B, n]
    const int* idx  = (const int*)d_in[2];    // [K], sorted

    const int B = 16;
    const int n = in_sizes[1] / B;   // 262144
    const int m = n - 1;             // 262143
    const int K = in_sizes[2];       // 131072
    const int NK = B * K;            // 2097152
    const int GRID = NK / CHUNK;     // 512 blocks = 2 per CU

    float* out   = (float*)d_out;
    float* phi   = out;                         // [B]
    float* v_out = out + B;                     // [B,K]
    float* r_out = v_out + (size_t)B * K;       // [B,m]
    float* w_out = r_out + (size_t)B * m;       // [B,m]

    char* ws = (char*)d_ws;
    unsigned long long* slotD = (unsigned long long*)ws;  ws += sizeof(unsigned long long) * 2 * GRID * 4;
    unsigned long long* slotK = (unsigned long long*)ws;  ws += sizeof(unsigned long long) * 2 * 2 * GRID;
    unsigned long long* slotV = (unsigned long long*)ws;  ws += sizeof(unsigned long long) * GRID;
    unsigned long long* slotP = (unsigned long long*)ws;  ws += sizeof(unsigned long long) * GRID;

    // one contiguous slot region, zeroed per call (tags restart each replay)
    hipMemsetAsync(slotD, 0,
                   sizeof(unsigned long long) * (2 * GRID * 4 + 2 * 2 * GRID + 2 * GRID),
                   stream);

    k_cg_pers<<<GRID, CGBLK, 0, stream>>>(idx, u, x, v_out, w_out, r_out, phi,
                                          slotD, slotK, slotV, slotP,
                                          n, K, B, GRID);
}

// Round 14
// 108.748 us; speedup vs baseline: 2.6909x; 1.0218x over previous
//
#include <hip/hip_runtime.h>
#include <math.h>

#define MAX_ITER 20
#define EPS_W 1e-3f
#define CLAMP_MIN 1e-4f
#define CLAMP_MAX 1e4f

#define E 16
#define CGBLK 256
#define CHUNK (E * CGBLK)  // 4096 elems/block; bpb = K/CHUNK = 32
#define SPAN_MAX 9216      // block i-span bound (mean 8193, sd ~64; 16 sigma)
#define PAD(t) ((t) + ((t) >> 5))   // +1-per-32 padding: kills stride-32 bank conflicts
#define SPAN_PAD (SPAN_MAX + SPAN_MAX / 32)  // 9504

// Per-block slot line: 128 u64 = 1KB, so each block's published words live on
// a private, interleave-aligned line (polls from 32 blocks hit 32 different
// memory homes -> no directory/channel contention). Word indices within line:
#define SLOT_STRIDE 128
#define W_D1 0
#define W_D2 1
#define W_RS0 2
#define W_EL 3   // left-edge value (kp[0]; r[0] at init on parity 1)
#define W_ER 4   // right-edge value (kp[E-1]; r[E-1] at init on parity 1)
#define W_V0 5   // epilogue: block's first v
#define W_PHI 6  // epilogue: block phi partial

__device__ __forceinline__ float sp_w(float u) {
    float sp = fmaxf(u, 0.f) + log1pf(expf(-fabsf(u)));
    float w = sp + EPS_W;
    return fminf(fmaxf(w, CLAMP_MIN), CLAMP_MAX);
}
__device__ __forceinline__ float nn(float x) { return (x == x) ? x : 0.f; }

// SYSTEM-scope relaxed atomics: cache-bypassing, coherence-point direct.
// (Measured r6->r7: poll rounds 21us -> 3.4us.)
__device__ __forceinline__ unsigned long long sys_ld64(const unsigned long long* p) {
    return __hip_atomic_load(p, __ATOMIC_RELAXED, __HIP_MEMORY_SCOPE_SYSTEM);
}
__device__ __forceinline__ unsigned long long sys_ld64_acq(const unsigned long long* p) {
    return __hip_atomic_load(p, __ATOMIC_ACQUIRE, __HIP_MEMORY_SCOPE_SYSTEM);
}
__device__ __forceinline__ void sys_st64(unsigned long long* p, unsigned long long v) {
    __hip_atomic_store(p, v, __ATOMIC_RELAXED, __HIP_MEMORY_SCOPE_SYSTEM);
}
__device__ __forceinline__ unsigned long long poll_tag(const unsigned long long* p, unsigned gen) {
    unsigned long long v; int s = 0;
    for (;;) {
        v = sys_ld64(p);
        if ((unsigned)(v >> 32) >= gen) return v;
        if ((++s & 63) == 0) {               // livelock insurance only
            v = sys_ld64_acq(p);
            if ((unsigned)(v >> 32) >= gen) return v;
        }
        __builtin_amdgcn_s_sleep(1);
    }
}
__device__ __forceinline__ unsigned long long mkword(unsigned gen, float f) {
    return ((unsigned long long)gen << 32) | (unsigned long long)__float_as_uint(f);
}
__device__ __forceinline__ float payload(unsigned long long v) {
    return __uint_as_float((unsigned)v);
}

// valid on tid 0 only; block = 256 threads (4 waves)
__device__ __forceinline__ float blockReduceSum(float v) {
    #pragma unroll
    for (int off = 32; off > 0; off >>= 1) v += __shfl_down(v, off, 64);
    __shared__ float smem[4];
    int lane = threadIdx.x & 63, wid = threadIdx.x >> 6;
    if (lane == 0) smem[wid] = v;
    __syncthreads();
    float r = 0.f;
    if (threadIdx.x == 0) r = smem[0] + smem[1] + smem[2] + smem[3];
    return r;
}
// paired reduction; valid on tid 0 only
__device__ __forceinline__ float2 blockReduceSum2(float a, float b) {
    #pragma unroll
    for (int off = 32; off > 0; off >>= 1) {
        a += __shfl_down(a, off, 64);
        b += __shfl_down(b, off, 64);
    }
    __shared__ float sa[4], sb[4];
    int lane = threadIdx.x & 63, wid = threadIdx.x >> 6;
    if (lane == 0) { sa[wid] = a; sb[wid] = b; }
    __syncthreads();
    float ra = 0.f, rb = 0.f;
    if (threadIdx.x == 0) {
        ra = sa[0] + sa[1] + sa[2] + sa[3];
        rb = sb[0] + sb[1] + sb[2] + sb[3];
    }
    return make_float2(ra, rb);
}

// Persistent single-reduction CG + fused pre/post; per-block 1KB slot lines.
// Plain launch (graph-capturable). Co-residency by capacity: waves_per_eu(2,2)
// + 78KB LDS -> exactly 2 blocks/CU, grid 512 = 2 x 256 CU (proven r5-r13).
__global__ __attribute__((amdgpu_flat_work_group_size(256, 256),
                          amdgpu_waves_per_eu(2, 2)))
void k_cg_pers(const int* __restrict__ idx, const float* __restrict__ u_all,
               const float* __restrict__ x, float* __restrict__ v_out,
               float* __restrict__ w_out, float* __restrict__ r_out,
               float* __restrict__ phi,
               unsigned long long* __restrict__ slot,   // [2][nblk][SLOT_STRIDE]
               int n, int K, int B, int nblk) {
    const int blk = blockIdx.x, tid = threadIdx.x;
    const int bpb = K / CHUNK;                  // 32
    const int b = blk / bpb, bbase = b * bpb;
    const bool first = (blk == bbase), last = (blk == bbase + bpb - 1);
    const int k0 = (blk - bbase) * CHUNK + tid * E;
    const int m = n - 1;
    const float* ub = u_all + (size_t)b * m;
    const float* xb = x + (size_t)b * n;

    auto SL = [&](int par, int blk_, int w) -> unsigned long long* {
        return slot + ((size_t)par * nblk + blk_) * SLOT_STRIDE + w;
    };

    __shared__ float sX[SPAN_PAD], sW[SPAN_PAD];
    __shared__ float sLa[CGBLK], sRa[CGBLK];
    __shared__ float sm[3];           // D1, D2, RS0
    __shared__ int sInfo[4];          // lo, len, jloB, jhiB
    __shared__ float sVN;             // next block's first v

    // ---- block i-span + coalesced staging: sX = nn(x), sW = sp_w(u) ----
    if (tid == 0) {
        int kblk = (blk - bbase) * CHUNK;
        int jlo = first ? 0 : idx[kblk];
        int jhi = last ? n : idx[kblk + CHUNK];
        int lo_ = (jlo > 0) ? jlo - 1 : 0;
        sInfo[0] = lo_;
        sInfo[1] = jhi - lo_;
        sInfo[2] = jlo;
        sInfo[3] = jhi;
    }
    __syncthreads();
    const int lo = sInfo[0], len = sInfo[1], jloB = sInfo[2], jhiB = sInfo[3];
    const bool staged = (len <= SPAN_MAX);
    if (staged) {
        for (int t = tid; t < len; t += CGBLK) {
            int i = lo + t;
            sX[PAD(t)] = nn(xb[i]);
            sW[PAD(t)] = (i < m) ? sp_w(ub[i]) : 0.f;
        }
        __syncthreads();
    }
    auto LXn = [&](int i) -> float { return staged ? sX[PAD(i - lo)] : nn(xb[i]); };
    auto LW  = [&](int i) -> float { return staged ? sW[PAD(i - lo)] : sp_w(ub[i]); };

    // ---- init: dg, cl, r0 in registers (LDS gathers, conflict-reduced) ----
    int jj[E + 2];
    {
        const int4* ip = reinterpret_cast<const int4*>(idx + k0);  // k0 % 16 == 0
        #pragma unroll
        for (int q4 = 0; q4 < E / 4; ++q4) {
            int4 t = ip[q4];
            jj[1 + 4 * q4] = t.x; jj[2 + 4 * q4] = t.y;
            jj[3 + 4 * q4] = t.z; jj[4 + 4 * q4] = t.w;
        }
        jj[0]     = (k0 > 0)      ? idx[k0 - 1] : -1000000;
        jj[E + 1] = (k0 + E < K)  ? idx[k0 + E] : -1000000;
    }
    float vv[E], r[E], p[E], kp[E], dgr[E], clr[E + 1];
    float s0 = 0.f;
    #pragma unroll
    for (int q = 0; q < E; ++q) {
        int j = jj[q + 1];
        bool la = (jj[q] == j - 1);
        bool ra = (jj[q + 2] == j + 1);
        float wl = 0.f, wr = 0.f;
        if (j >= 1)     { float w = LW(j - 1); wl = w * w; }
        if (j <= n - 2) { float w = LW(j);     wr = w * w; }
        float rhs = 0.f;
        if (j >= 1 && !la)     rhs += wl * LXn(j - 1);
        if (j <= n - 2 && !ra) rhs += wr * LXn(j + 1);
        vv[q] = 0.f; r[q] = rhs; p[q] = 0.f; kp[q] = 0.f;
        dgr[q] = wl + wr;
        clr[q] = la ? wl : 0.f;
        s0 += rhs * rhs;
    }
    {
        float cl8 = 0.f;
        int j8 = jj[E + 1];
        if ((k0 + E) < K && jj[E] == j8 - 1) { float w = LW(j8 - 1); cl8 = w * w; }
        clr[E] = cl8;
    }
    // publish initial r-edges (tag 1, parity-1 line words EL/ER)
    if (tid == 0)         sys_st64(SL(1, blk, W_EL), mkword(1u, r[0]));
    if (tid == CGBLK - 1) sys_st64(SL(1, blk, W_ER), mkword(1u, r[E - 1]));

    float s0b = blockReduceSum(s0);   // tid0; published with round 0

    float rs = 0.f, beta = 0.f;
    float r_nbL = 0.f, p_nbL = 0.f;   // live in tid 0
    float r_nbR = 0.f, p_nbR = 0.f;   // live in tid 255

    for (int it = 0; it < MAX_ITER; ++it) {
        const unsigned G = (unsigned)(it + 2);
        const int par = it & 1;
        if (it == 0) {   // fetch neighbor r0 edges (self-tagged)
            if (tid == 0 && !first)
                r_nbL = payload(poll_tag(SL(1, blk - 1, W_ER), 1u));
            if (tid == CGBLK - 1 && !last)
                r_nbR = payload(poll_tag(SL(1, blk + 1, W_EL), 1u));
        }
        // p update (beta=0 at it=0) + bitwise neighbor mirror
        #pragma unroll
        for (int q = 0; q < E; ++q) p[q] = r[q] + beta * p[q];
        if (tid == 0)         p_nbL = r_nbL + beta * p_nbL;
        if (tid == CGBLK - 1) p_nbR = r_nbR + beta * p_nbR;
        sLa[tid] = p[0]; sRa[tid] = p[E - 1];
        __syncthreads();
        float pl = (tid > 0) ? sRa[tid - 1] : (first ? 0.f : p_nbL);
        float pr = (tid < CGBLK - 1) ? sLa[tid + 1] : (last ? 0.f : p_nbR);
        float d1 = 0.f, d2 = 0.f;
        #pragma unroll
        for (int q = 0; q < E; ++q) {
            float pm = (q == 0) ? pl : p[q - 1];
            float pp = (q == E - 1) ? pr : p[q + 1];
            kp[q] = dgr[q] * p[q] - clr[q] * pm - clr[q + 1] * pp;
            d1 += p[q] * kp[q];
            d2 += kp[q] * kp[q];
        }
        // publish Kp edges early (gen-tagged, parity-buffered, own line)
        if (tid == 0)         sys_st64(SL(par, blk, W_EL), mkword(G, kp[0]));
        if (tid == CGBLK - 1) sys_st64(SL(par, blk, W_ER), mkword(G, kp[E - 1]));
        float2 db = blockReduceSum2(d1, d2);
        if (tid == 0) {
            sys_st64(SL(par, blk, W_D1), mkword(G, db.x));
            sys_st64(SL(par, blk, W_D2), mkword(G, db.y));
            if (it == 0) sys_st64(SL(0, blk, W_RS0), mkword(G, s0b));
        }
        // ---- all-to-all poll: one fabric hop, 32 distinct lines ----
        float kpnbl = 0.f, kpnbr = 0.f;
        {
            int lane = tid & 63, wid = tid >> 6;
            if (wid == 0) {
                int which = (lane >> 5) ? W_D2 : W_D1;
                int li = lane & 31;
                float pv = 0.f;
                if (li < bpb)
                    pv = payload(poll_tag(SL(par, bbase + li, which), G));
                #pragma unroll
                for (int off = 16; off > 0; off >>= 1) pv += __shfl_down(pv, off, 32);
                if (lane == 0)  sm[0] = pv;
                if (lane == 32) sm[1] = pv;
            } else if (wid == 1 && it == 0 && lane < 32) {
                float pv = 0.f;
                if (lane < bpb)
                    pv = payload(poll_tag(SL(0, bbase + lane, W_RS0), 2u));
                #pragma unroll
                for (int off = 16; off > 0; off >>= 1) pv += __shfl_down(pv, off, 32);
                if (lane == 0) sm[2] = pv;
            }
            if (tid == 0 && !first)
                kpnbl = payload(poll_tag(SL(par, blk - 1, W_ER), G));
            if (tid == CGBLK - 1 && !last)
                kpnbr = payload(poll_tag(SL(par, blk + 1, W_EL), G));
        }
        __syncthreads();
        float D1 = sm[0], D2 = sm[1];
        if (it == 0) rs = sm[2];
        float alpha = rs / (D1 + 1e-30f);
        float rs_new = fmaxf(alpha * alpha * D2 - rs, 0.f);
        #pragma unroll
        for (int q = 0; q < E; ++q) {
            vv[q] += alpha * p[q];
            r[q]  -= alpha * kp[q];
        }
        if (tid == 0 && !first)        r_nbL -= alpha * kpnbl;
        if (tid == CGBLK - 1 && !last) r_nbR -= alpha * kpnbr;
        beta = rs_new / (rs + 1e-30f);
        rs = rs_new;
    }

    // ---- publish v0 early; v writeout (coalesced) ----
    const unsigned FG = (unsigned)(MAX_ITER + 2);   // 22
    if (tid == 0) sys_st64(SL(0, blk, W_V0), mkword(FG, vv[0]));
    float* vb = v_out + (size_t)b * K + (size_t)(blk - bbase) * CHUNK + (size_t)tid * E;
    #pragma unroll
    for (int q4 = 0; q4 < E / 4; ++q4)
        reinterpret_cast<float4*>(vb)[q4] =
            make_float4(vv[4 * q4], vv[4 * q4 + 1], vv[4 * q4 + 2], vv[4 * q4 + 3]);

    // reload idx window (init's jj may have been re-used by regalloc)
    int jl[E + 1];
    {
        const int4* ip = reinterpret_cast<const int4*>(idx + k0);
        #pragma unroll
        for (int q4 = 0; q4 < E / 4; ++q4) {
            int4 t = ip[q4];
            jl[4 * q4] = t.x; jl[4 * q4 + 1] = t.y;
            jl[4 * q4 + 2] = t.z; jl[4 * q4 + 3] = t.w;
        }
        jl[E] = (k0 + E < K) ? idx[k0 + E] : n;
    }

    float* wb = w_out + (size_t)b * m;
    float* rb = r_out + (size_t)b * m;
    float phi_acc = 0.f;

    if (staged) {
        // scatter register v into padded span (padding spreads the ~32-stride)
        if (tid == CGBLK - 1)
            sVN = last ? 0.f : payload(poll_tag(SL(0, blk + 1, W_V0), FG));
        #pragma unroll
        for (int q = 0; q < E; ++q) sX[PAD(jl[q] - lo)] = vv[q];
        __syncthreads();
        // coalesced pass: r = D(s), w from sW, phi accumulate, coalesced stores
        int tLo = jloB - lo;
        int wrHi = (jhiB < m) ? jhiB : m;
        int tHi = wrHi - lo;
        float vnext = sVN;
        for (int t = tLo + tid; t < tHi; t += CGBLK) {
            int i = lo + t;
            float s_cur = sX[PAD(t)];
            float s_next = (i + 1 == jhiB) ? vnext : sX[PAD(t + 1)];
            float w = sW[PAD(t)];
            float rv = s_next - s_cur;
            wb[i] = w;
            rb[i] = rv;
            phi_acc += w * w * rv * rv;
        }
    } else {
        // fallback (len > SPAN_MAX, ~impossible): serial walk on global
        sLa[tid] = vv[0];
        __syncthreads();
        float v_next = 0.f;
        if (tid < CGBLK - 1)      v_next = sLa[tid + 1];
        else if (!last)           v_next = payload(poll_tag(SL(0, blk + 1, W_V0), FG));
        const bool first_thread = first && (tid == 0);
        const bool last_thread  = last && (tid == CGBLK - 1);
        int j_lo = first_thread ? 0 : jl[0];
        int j_hi = last_thread ? n : jl[E];
        int kptr = 0;
        int i = j_lo;
        float s_cur;
        if (kptr < E && i == jl[kptr]) { s_cur = vv[kptr]; ++kptr; }
        else s_cur = nn(xb[i]);
        while (i < j_hi) {
            int ip = i + 1;
            float s_next;
            if (ip == j_hi) s_next = v_next;
            else if (kptr < E && ip == jl[kptr]) { s_next = vv[kptr]; ++kptr; }
            else s_next = nn(xb[ip]);
            if (i < m) {
                float wv = sp_w(ub[i]);
                float rv = s_next - s_cur;
                wb[i] = wv;
                rb[i] = rv;
                phi_acc += wv * wv * rv * rv;
            }
            s_cur = s_next;
            i = ip;
        }
    }

    // phi: one tagged all-to-all round; batch leader is single writer
    float pblk = blockReduceSum(phi_acc);
    if (tid == 0) sys_st64(SL(0, blk, W_PHI), mkword(FG, pblk));
    if (first) {
        int lane = tid & 63, wid = tid >> 6;
        if (wid == 0) {
            float pv = 0.f;
            if (lane < bpb)
                pv = payload(poll_tag(SL(0, bbase + lane, W_PHI), FG));
            #pragma unroll
            for (int off = 16; off > 0; off >>= 1) pv += __shfl_down(pv, off, 32);
            if (lane == 0) phi[b] = pv;
        }
    }
}

extern "C" void kernel_launch(void* const* d_in, const int* in_sizes, int n_in,
                              void* d_out, int out_size, void* d_ws, size_t ws_size,
                              hipStream_t stream) {
    const float* u  = (const float*)d_in[0];  // [B, n-1]
    const float* x  = (const float*)d_in[1];  // [B, n]
    const int* idx  = (const int*)d_in[2];    // [K], sorted

    const int B = 16;
    const int n = in_sizes[1] / B;   // 262144
    const int m = n - 1;             // 262143
    const int K = in_sizes[2];       // 131072
    const int NK = B * K;            // 2097152
    const int GRID = NK / CHUNK;     // 512 blocks = 2 per CU

    float* out   = (float*)d_out;
    float* phi   = out;                         // [B]
    float* v_out = out + B;                     // [B,K]
    float* r_out = v_out + (size_t)B * K;       // [B,m]
    float* w_out = r_out + (size_t)B * m;       // [B,m]

    char* ws = (char*)d_ws;
    unsigned long long* slot = (unsigned long long*)ws;
    size_t slot_words = (size_t)2 * GRID * SLOT_STRIDE;   // 1MB

    // zero the slot region each call (tags restart every replay)
    hipMemsetAsync(slot, 0, sizeof(unsigned long long) * slot_words, stream);

    k_cg_pers<<<GRID, CGBLK, 0, stream>>>(idx, u, x, v_out, w_out, r_out, phi,
                                          slot, n, K, B, GRID);
}